// Round 6
// baseline (324.124 us; speedup 1.0000x reference)
//
#include <hip/hip_runtime.h>
#include <cstdint>
#include <cstddef>

#define D_MODEL 1024
#define N_EXPERTS 8
#define FFN_H 2048
#define N_TOK 4096
#define CAP 2048

typedef float f32x4 __attribute__((ext_vector_type(4)));
typedef __bf16 bf16x8 __attribute__((ext_vector_type(8)));

// ---- workspace layout (bytes) ----
static constexpr size_t XB_OFF   = 0;                                                  // [N][D] bf16
static constexpr size_t W1B_OFF  = XB_OFF  + (size_t)N_TOK * D_MODEL * 2;
static constexpr size_t W2B_OFF  = W1B_OFF + (size_t)N_EXPERTS * FFN_H * D_MODEL * 2;
static constexpr size_t HBUF_OFF = W2B_OFF + (size_t)N_EXPERTS * D_MODEL * FFN_H * 2;  // [E][CAP][H] bf16
static constexpr size_t YBUF_OFF = HBUF_OFF + (size_t)N_EXPERTS * CAP * FFN_H * 2;     // [E][CAP][D] bf16
static constexpr size_t CNT_OFF  = YBUF_OFF + (size_t)N_EXPERTS * CAP * D_MODEL * 2;   // [8] int
static constexpr size_t PSUM_OFF = CNT_OFF + 32;                                       // [8] float
static constexpr size_t TOK_OFF  = PSUM_OFF + 32;                                      // [E][CAP] int
static constexpr size_t TIX_OFF  = TOK_OFF + (size_t)N_EXPERTS * CAP * 4;              // [N] int2
static constexpr size_t TIW_OFF  = TIX_OFF + (size_t)N_TOK * 8;                        // [N] float2

// async global->LDS, 16 B per lane; LDS dest = wave-uniform base + lane*16
__device__ __forceinline__ void async_ld16(const void* g, void* l) {
    __builtin_amdgcn_global_load_lds(
        (const __attribute__((address_space(1))) unsigned int*)g,
        (__attribute__((address_space(3))) unsigned int*)l, 16, 0, 0);
}

// ---------------- fused prep: blocks 0..63 = router (+x cvt); 64.. = w1/w2 cvt ----------------
__global__ __launch_bounds__(256) void prep_kernel(const float* __restrict__ x,
                                                   const float* __restrict__ rw,
                                                   const float* __restrict__ w1,
                                                   const float* __restrict__ w2,
                                                   __bf16* __restrict__ xb,
                                                   __bf16* __restrict__ w1b,
                                                   __bf16* __restrict__ w2b,
                                                   int* __restrict__ counts,
                                                   float* __restrict__ psum,
                                                   int* __restrict__ tok_list,
                                                   int2* __restrict__ tinfo_idx,
                                                   float2* __restrict__ tinfo_w) {
    __shared__ float rws[N_EXPERTS * D_MODEL];   // 32 KB (router blocks only)
    __shared__ int s_e0[64], s_e1[64], s_r0[64], s_r1[64];
    __shared__ float s_w0[64], s_w1[64];
    __shared__ int hist[8], base[8];
    __shared__ float pacc[8];

    int tid = threadIdx.x;
    int b = blockIdx.x;
    if (b >= 64) {
        // ---- w1/w2 conversion path ----
        int c = b - 64;
        const float* src; __bf16* dst; size_t bb;
        if (c < 8192) { src = w1; dst = w1b; bb = (size_t)c * 2048; }
        else          { src = w2; dst = w2b; bb = (size_t)(c - 8192) * 2048; }
        size_t i = bb + (size_t)tid * 8;
        float4 a = *reinterpret_cast<const float4*>(src + i);
        float4 d = *reinterpret_cast<const float4*>(src + i + 4);
        bf16x8 r;
        r[0] = (__bf16)a.x; r[1] = (__bf16)a.y; r[2] = (__bf16)a.z; r[3] = (__bf16)a.w;
        r[4] = (__bf16)d.x; r[5] = (__bf16)d.y; r[6] = (__bf16)d.z; r[7] = (__bf16)d.w;
        *reinterpret_cast<bf16x8*>(dst + i) = r;
        return;
    }

    // ---- router path: 64 tokens per block; also converts x rows to bf16 ----
    {
        size_t base_i = (size_t)b * 64 * D_MODEL;
        for (int i = tid; i < 64 * D_MODEL / 8; i += 256) {
            size_t off = base_i + (size_t)i * 8;
            float4 a = *reinterpret_cast<const float4*>(x + off);
            float4 d = *reinterpret_cast<const float4*>(x + off + 4);
            bf16x8 r;
            r[0] = (__bf16)a.x; r[1] = (__bf16)a.y; r[2] = (__bf16)a.z; r[3] = (__bf16)a.w;
            r[4] = (__bf16)d.x; r[5] = (__bf16)d.y; r[6] = (__bf16)d.z; r[7] = (__bf16)d.w;
            *reinterpret_cast<bf16x8*>(xb + off) = r;
        }
    }
    for (int i = tid * 4; i < N_EXPERTS * D_MODEL; i += 256 * 4)
        *reinterpret_cast<float4*>(&rws[i]) = *reinterpret_cast<const float4*>(&rw[i]);
    if (tid < 8) { hist[tid] = 0; pacc[tid] = 0.f; }
    __syncthreads();

    int wave = tid >> 6, lane = tid & 63;
    float psacc[8] = {};
    for (int it = 0; it < 16; ++it) {
        int li = wave * 16 + it;
        int t = b * 64 + li;
        const float* xr = x + (size_t)t * D_MODEL;
        float acc[8] = {};
#pragma unroll
        for (int i = 0; i < D_MODEL / 64; ++i) {
            float xv = xr[lane + 64 * i];
#pragma unroll
            for (int e = 0; e < 8; ++e) acc[e] += xv * rws[e * D_MODEL + lane + 64 * i];
        }
        float logit[8];
#pragma unroll
        for (int e = 0; e < 8; ++e) {
            float v = acc[e];
            for (int off = 32; off; off >>= 1) v += __shfl_xor(v, off);
            logit[e] = v;
        }
        float mx = logit[0];
#pragma unroll
        for (int e = 1; e < 8; ++e) mx = fmaxf(mx, logit[e]);
        float p[8], s = 0.f;
#pragma unroll
        for (int e = 0; e < 8; ++e) { p[e] = expf(logit[e] - mx); s += p[e]; }
        float inv = 1.f / s;
#pragma unroll
        for (int e = 0; e < 8; ++e) { p[e] *= inv; psacc[e] += p[e]; }
        int e0 = 0; float p0 = p[0];
#pragma unroll
        for (int e = 1; e < 8; ++e) if (p[e] > p0) { p0 = p[e]; e0 = e; }
        int e1 = -1; float p1 = -1.f;
#pragma unroll
        for (int e = 0; e < 8; ++e) if (e != e0 && p[e] > p1) { p1 = p[e]; e1 = e; }
        float invw = 1.f / (p0 + p1);
        if (lane == 0) {
            s_e0[li] = e0; s_e1[li] = e1;
            s_w0[li] = p0 * invw; s_w1[li] = p1 * invw;
        }
    }
    if (lane == 0)
#pragma unroll
        for (int e = 0; e < 8; ++e) atomicAdd(&pacc[e], psacc[e]);
    __syncthreads();

    if (tid < 64) {
        s_r0[tid] = atomicAdd(&hist[s_e0[tid]], 1);
        s_r1[tid] = atomicAdd(&hist[s_e1[tid]], 1);
    }
    __syncthreads();
    if (tid < 8) {
        base[tid] = atomicAdd(&counts[tid], hist[tid]);   // device-scope, 512 total
        atomicAdd(&psum[tid], pacc[tid]);
    }
    __syncthreads();
    if (tid < 64) {
        int t = b * 64 + tid;
        int e0 = s_e0[tid], e1 = s_e1[tid];
        int q0 = min(base[e0] + s_r0[tid], CAP - 1);
        int q1 = min(base[e1] + s_r1[tid], CAP - 1);
        tok_list[e0 * CAP + q0] = t;
        tok_list[e1 * CAP + q1] = t;
        tinfo_idx[t] = make_int2(e0 * CAP + q0, e1 * CAP + q1);
        tinfo_w[t] = make_float2(s_w0[tid], s_w1[tid]);
    }
}

// ---------------- grouped GEMM, 128x128 tile, BK=32, global_load_lds, XCD swizzle ----------------
// Epilogue stages C through padded LDS for coalesced 16-B stores.
template <int KDIM, bool PASS2>
__global__ __launch_bounds__(256) void ffn_kernel(const __bf16* __restrict__ A_base,
                                                  const __bf16* __restrict__ B_base,
                                                  const float* __restrict__ bias,
                                                  const int* __restrict__ counts,
                                                  const int* __restrict__ tok_list,
                                                  __bf16* __restrict__ Out_base) {
    constexpr int BROWS = PASS2 ? D_MODEL : FFN_H;
    constexpr int OSTRIDE = PASS2 ? D_MODEL : FFN_H;
    constexpr int NT = BROWS / 128;
    constexpr int CSTR = 136;         // padded C-tile stride (bf16) -> rows shift banks by 4
    int bid = blockIdx.x;
    int e = bid & 7;                  // expert fastest -> XCD-pinned weights
    int r = bid >> 3;
    int n0 = (r % NT) * 128;
    int m0 = (r / NT) * 128;
    int cnt = min(counts[e], CAP);
    if (m0 >= cnt) return;

    // union: staging (s_a 4096 elems | s_b 4096 elems) / epilogue C half-tile 64x136
    __shared__ __bf16 s_buf[64 * CSTR];   // 17408 B
    __shared__ int s_tok[128];

    int tid = threadIdx.x;
    if (!PASS2 && tid < 128) {
        int slot = min(m0 + tid, cnt - 1);
        s_tok[tid] = tok_list[e * CAP + slot];
    }
    __syncthreads();

    int colk = (tid & 3) * 8;
    const __bf16 *a_src0, *a_src1;
    if (PASS2) {
        int s0 = min(m0 + (tid >> 2), cnt - 1);
        int s1 = min(m0 + 64 + (tid >> 2), cnt - 1);
        a_src0 = A_base + ((size_t)e * CAP + s0) * KDIM + colk;
        a_src1 = A_base + ((size_t)e * CAP + s1) * KDIM + colk;
    } else {
        a_src0 = A_base + (size_t)s_tok[tid >> 2] * KDIM + colk;
        a_src1 = A_base + (size_t)s_tok[64 + (tid >> 2)] * KDIM + colk;
    }
    const __bf16* b_src0 = B_base + ((size_t)e * BROWS + n0 + (tid >> 2)) * KDIM + colk;
    const __bf16* b_src1 = b_src0 + (size_t)64 * KDIM;

    char* lds_a = (char*)s_buf + (tid >> 6) * 1024;
    char* lds_b = (char*)s_buf + 8192 + (tid >> 6) * 1024;

    int wv = tid >> 6, lane = tid & 63;
    int wm = wv >> 1, wn = wv & 1;
    int lm = lane & 15, q = lane >> 4;
    int a_base = (wm * 64 + lm) * 32 + q * 8;
    int b_base = 4096 + (wn * 64 + lm) * 32 + q * 8;

    f32x4 acc[4][4] = {};
    for (int k0 = 0; k0 < KDIM; k0 += 32) {
        async_ld16(a_src0 + k0, lds_a);
        async_ld16(a_src1 + k0, lds_a + 4096);
        async_ld16(b_src0 + k0, lds_b);
        async_ld16(b_src1 + k0, lds_b + 4096);
        __syncthreads();
        bf16x8 af[4], bf[4];
#pragma unroll
        for (int f = 0; f < 4; ++f) {
            af[f] = *reinterpret_cast<const bf16x8*>(&s_buf[a_base + f * 16 * 32]);
            bf[f] = *reinterpret_cast<const bf16x8*>(&s_buf[b_base + f * 16 * 32]);
        }
#pragma unroll
        for (int fm = 0; fm < 4; ++fm)
#pragma unroll
            for (int fn = 0; fn < 4; ++fn)
                acc[fm][fn] = __builtin_amdgcn_mfma_f32_16x16x32_bf16(af[fm], bf[fn], acc[fm][fn], 0, 0, 0);
        __syncthreads();
    }

    // ---- epilogue: two 64-row phases through LDS, coalesced 16-B global stores ----
#pragma unroll
    for (int h = 0; h < 2; ++h) {
        if (wm == h) {
#pragma unroll
            for (int fn = 0; fn < 4; ++fn) {
                int col = wn * 64 + fn * 16 + lm;
                float bv = bias[e * BROWS + n0 + col];
#pragma unroll
                for (int fm = 0; fm < 4; ++fm) {
                    int rloc = fm * 16 + q * 4;
#pragma unroll
                    for (int i = 0; i < 4; ++i) {
                        float v = acc[fm][fn][i] + bv;
                        if (!PASS2) v = v / (1.f + __expf(-v));
                        s_buf[(rloc + i) * CSTR + col] = (__bf16)v;
                    }
                }
            }
        }
        __syncthreads();
        // cooperative store: 64 rows x 128 cols bf16; 16 lanes cover one row (256 B)
#pragma unroll
        for (int j = 0; j < 4; ++j) {
            int rloc = (tid >> 4) + j * 16;
            int coloff = (tid & 15) * 8;
            int slot = m0 + h * 64 + rloc;
            if (slot < cnt) {
                bf16x8 vv = *reinterpret_cast<const bf16x8*>(&s_buf[rloc * CSTR + coloff]);
                *reinterpret_cast<bf16x8*>(
                    Out_base + ((size_t)e * CAP + slot) * OSTRIDE + n0 + coloff) = vv;
            }
        }
        __syncthreads();
    }
}

// ---------------- combine: out[t] = w0*y[idx0] + w1*y[idx1]; block 0 thread 0 does aux ----------------
__global__ __launch_bounds__(256) void combine_kernel(const __bf16* __restrict__ ybuf,
                                                      const int2* __restrict__ tinfo_idx,
                                                      const float2* __restrict__ tinfo_w,
                                                      const int* __restrict__ counts,
                                                      const float* __restrict__ psum,
                                                      float* __restrict__ out) {
    int tid = threadIdx.x;
    if (blockIdx.x == 0 && tid == 0) {
        float s = 0.f;
#pragma unroll
        for (int e = 0; e < 8; ++e)
            s += ((float)counts[e] / (float)(N_TOK * 2)) * (psum[e] / (float)N_TOK);
        out[(size_t)N_TOK * D_MODEL] = 8.f * s;
    }
    int t = blockIdx.x * 2 + (tid >> 7);
    int d0 = (tid & 127) * 8;
    int2 ix = tinfo_idx[t];
    float2 w = tinfo_w[t];
    bf16x8 ya = *reinterpret_cast<const bf16x8*>(ybuf + (size_t)ix.x * D_MODEL + d0);
    bf16x8 yb = *reinterpret_cast<const bf16x8*>(ybuf + (size_t)ix.y * D_MODEL + d0);
    float4 o0, o1;
    o0.x = w.x * (float)ya[0] + w.y * (float)yb[0];
    o0.y = w.x * (float)ya[1] + w.y * (float)yb[1];
    o0.z = w.x * (float)ya[2] + w.y * (float)yb[2];
    o0.w = w.x * (float)ya[3] + w.y * (float)yb[3];
    o1.x = w.x * (float)ya[4] + w.y * (float)yb[4];
    o1.y = w.x * (float)ya[5] + w.y * (float)yb[5];
    o1.z = w.x * (float)ya[6] + w.y * (float)yb[6];
    o1.w = w.x * (float)ya[7] + w.y * (float)yb[7];
    float* op = out + (size_t)t * D_MODEL + d0;
    *reinterpret_cast<float4*>(op) = o0;
    *reinterpret_cast<float4*>(op + 4) = o1;
}

extern "C" void kernel_launch(void* const* d_in, const int* in_sizes, int n_in,
                              void* d_out, int out_size, void* d_ws, size_t ws_size,
                              hipStream_t stream) {
    const float* x  = (const float*)d_in[0];
    const float* rw = (const float*)d_in[1];
    const float* w1 = (const float*)d_in[2];
    const float* b1 = (const float*)d_in[3];
    const float* w2 = (const float*)d_in[4];
    const float* b2 = (const float*)d_in[5];
    float* out = (float*)d_out;

    char* ws = (char*)d_ws;
    __bf16* xb     = (__bf16*)(ws + XB_OFF);
    __bf16* w1b    = (__bf16*)(ws + W1B_OFF);
    __bf16* w2b    = (__bf16*)(ws + W2B_OFF);
    __bf16* hbuf   = (__bf16*)(ws + HBUF_OFF);
    __bf16* ybuf   = (__bf16*)(ws + YBUF_OFF);
    int*    counts = (int*)(ws + CNT_OFF);
    float*  psum   = (float*)(ws + PSUM_OFF);
    int*    tok    = (int*)(ws + TOK_OFF);
    int2*   tix    = (int2*)(ws + TIX_OFF);
    float2* tiw    = (float2*)(ws + TIW_OFF);

    hipMemsetAsync(ws + CNT_OFF, 0, 64, stream);   // counts + psum

    prep_kernel<<<64 + 16384, 256, 0, stream>>>(x, rw, w1, w2, xb, w1b, w2b,
                                                counts, psum, tok, tix, tiw);

    ffn_kernel<D_MODEL, false><<<8 * (FFN_H / 128) * (CAP / 128), 256, 0, stream>>>(
        xb, w1b, b1, counts, tok, hbuf);
    ffn_kernel<FFN_H, true><<<8 * (D_MODEL / 128) * (CAP / 128), 256, 0, stream>>>(
        hbuf, w2b, b2, counts, tok, ybuf);

    combine_kernel<<<N_TOK / 2, 256, 0, stream>>>(ybuf, tix, tiw, counts, psum, out);
}